// Round 3
// baseline (65.537 us; speedup 1.0000x reference)
//
#include <hip/hip_runtime.h>
#include <hip/hip_bf16.h>

#define DM 1024
#define SD 32
#define NG 8
#define GD 128
#define BS 4
#define TT 4096
#define CL 64        // chunk length
#define NC (TT/CL)   // 64 chunks

typedef __attribute__((ext_vector_type(8))) short short8;
typedef __attribute__((ext_vector_type(4))) float f32x4;

// workspace layout (bytes), 16B aligned
#define WS_POWA  0                         // f32[8][64][32]  = 64KB  (powA[g][t][n] = Abar^(t+1))
#define WS_STL   65536                     // bf16[4][64][8][64][32] = 8MB (local-scan states)
#define WS_CARRY (WS_STL + 8388608)        // f32[4][64][8][32] = 256KB

__device__ __forceinline__ unsigned short f2bf(float f) {
  unsigned u = __float_as_uint(f);
  unsigned r = (u + 0x7FFFu + ((u >> 16) & 1u)) >> 16;   // RNE
  return (unsigned short)r;
}
__device__ __forceinline__ float bf2f(unsigned short h) {
  return __uint_as_float(((unsigned)h) << 16);
}
__device__ __forceinline__ float softplus_f(float x) {
  return (x > 20.f) ? x : log1pf(expf(x));
}
__device__ __forceinline__ short8 pack8(float4 a, float4 b) {
  short8 h;
  h[0]=(short)f2bf(a.x); h[1]=(short)f2bf(a.y); h[2]=(short)f2bf(a.z); h[3]=(short)f2bf(a.w);
  h[4]=(short)f2bf(b.x); h[5]=(short)f2bf(b.y); h[6]=(short)f2bf(b.z); h[7]=(short)f2bf(b.w);
  return h;
}

// ---------------- KA: Bu GEMM (4-wave m-split) + two-level scan ----------------
__global__ __launch_bounds__(256) void ka_bu_scan(const float* __restrict__ u,
                                                  const float* __restrict__ A_log,
                                                  const float* __restrict__ B_param,
                                                  const float* __restrict__ dt_logit,
                                                  unsigned char* __restrict__ ws) {
  const int bx = blockIdx.x;
  const int c = bx & (NC - 1);
  const int g = (bx >> 6) & (NG - 1);
  const int b = bx >> 9;
  const int tid = threadIdx.x;
  const int w = tid >> 6;          // wave 0..3 -> m-tile w (t in [16w,16w+16))
  const int l = tid & 63;
  const int lr = l & 15, lh = l >> 4;

  const float dtg = 0.001f + 0.099f * (1.f / (1.f + expf(-dt_logit[g])));

  // frac for the two B-operand n's this lane touches (n = nt*16 + lr)
  float fracv[2];
  #pragma unroll
  for (int nt = 0; nt < 2; ++nt) {
    int n = nt * 16 + lr;
    float A = -softplus_f(A_log[g * SD + n]);
    float a = expf(A * dtg);
    fracv[nt] = (fabsf(A) > 1e-6f) ? (a - 1.f) / A : dtg;
  }
  // scan decay for n = l&31
  float a_scan;
  {
    float A = -softplus_f(A_log[g * SD + (l & 31)]);
    a_scan = expf(A * dtg);
  }

  // GEMM: this wave computes Bu rows t = w*16 + lr, all 32 n, K=128
  const float* up = u + ((size_t)b * TT + (size_t)c * CL) * DM + g * GD;
  const float* bp = B_param + (size_t)g * SD * GD;
  f32x4 acc[2];
  #pragma unroll
  for (int nt = 0; nt < 2; ++nt)
    #pragma unroll
    for (int j = 0; j < 4; ++j) acc[nt][j] = 0.f;

  #pragma unroll
  for (int kt = 0; kt < 4; ++kt) {
    // A fragment from u
    const float* pa = up + (size_t)(w * 16 + lr) * DM + kt * 32 + lh * 8;
    float4 a0 = *(const float4*)pa;
    float4 a1 = *(const float4*)(pa + 4);
    short8 af = pack8(a0, a1);
    // B fragments (scaled B_param), used once each
    #pragma unroll
    for (int nt = 0; nt < 2; ++nt) {
      const float* pb = bp + (size_t)(nt * 16 + lr) * GD + kt * 32 + lh * 8;
      float4 v0 = *(const float4*)pb;
      float4 v1 = *(const float4*)(pb + 4);
      float s = fracv[nt];
      v0.x*=s; v0.y*=s; v0.z*=s; v0.w*=s;
      v1.x*=s; v1.y*=s; v1.z*=s; v1.w*=s;
      short8 bf8 = pack8(v0, v1);
      acc[nt] = __builtin_amdgcn_mfma_f32_16x16x32_bf16(af, bf8, acc[nt], 0, 0, 0);
    }
  }

  __shared__ __align__(16) float sBu[CL * 33];             // 8448B
  __shared__ __align__(16) unsigned short sSt[CL * SD];    // 4096B
  __shared__ __align__(16) float sc[4][SD];                // 512B segment carries

  #pragma unroll
  for (int nt = 0; nt < 2; ++nt)
    #pragma unroll
    for (int j = 0; j < 4; ++j) {
      int t = w * 16 + lh * 4 + j;   // C/D: row=(lane>>4)*4+j
      int n = nt * 16 + lr;          //      col=lane&15
      sBu[t * 33 + n] = acc[nt][j];
    }
  __syncthreads();

  // two-level scan: each wave scans its 16 t's (zero init), then segment fix
  float sreg[16];
  if (l < SD) {
    float s = 0.f;
    #pragma unroll
    for (int t = 0; t < 16; ++t) {
      s = fmaf(s, a_scan, sBu[(w * 16 + t) * 33 + l]);
      sreg[t] = s;
    }
    sc[w][l] = s;
  }
  __syncthreads();

  float* carry = (float*)(ws + WS_CARRY);
  if (l < SD) {
    float a2 = a_scan * a_scan, a4 = a2 * a2, a8 = a4 * a4, a16 = a8 * a8;
    float pfx = 0.f;
    for (int v = 0; v < w; ++v) pfx = fmaf(pfx, a16, sc[v][l]);
    float pw = 1.f;
    #pragma unroll
    for (int t = 0; t < 16; ++t) {
      pw *= a_scan;
      sSt[(w * 16 + t) * SD + l] = f2bf(fmaf(pw, pfx, sreg[t]));
    }
    if (w == 3)
      carry[((b * NC + c) * NG + g) * SD + l] = fmaf(a16, pfx, sreg[15]);
  }
  __syncthreads();

  // states -> global (bf16): 2048 ushorts, one short8 per thread
  unsigned short* stg = (unsigned short*)(ws + WS_STL) + ((size_t)((b * NC + c) * NG + g)) * CL * SD;
  *(short8*)(stg + tid * 8) = *(short8*)(sSt + tid * 8);

  // 8 special blocks emit powA for KB
  if (b == 0 && c == 0 && tid < SD) {
    float* powA = (float*)(ws + WS_POWA);
    float p = 1.f;
    #pragma unroll
    for (int t = 0; t < CL; ++t) {
      p *= a_scan;
      powA[(g * CL + t) * SD + tid] = p;
    }
  }
}

// ---------------- KB: chunk prefix + correction + C GEMM (4-wave d-split) ----------------
__global__ __launch_bounds__(256) void kb_y(const float* __restrict__ u,
                                            const float* __restrict__ state0,
                                            const float* __restrict__ C,
                                            const float* __restrict__ Dp,
                                            unsigned char* __restrict__ ws,
                                            float* __restrict__ y,
                                            float* __restrict__ sfin) {
  const int bx = blockIdx.x;
  const int c = bx & (NC - 1);
  const int g = (bx >> 6) & (NG - 1);
  const int b = bx >> 9;
  const int tid = threadIdx.x;
  const int w = tid >> 6;          // wave 0..3 -> d-tiles {w, w+4}
  const int l = tid & 63;
  const int lr = l & 15, lh = l >> 4;
  const int n = l & 31;

  const float* powA = (const float*)(ws + WS_POWA) + g * CL * SD;
  const float* carry = (const float*)(ws + WS_CARRY);
  const unsigned short* stg = (const unsigned short*)(ws + WS_STL) + ((size_t)((b * NC + c) * NG + g)) * CL * SD;

  // --- chunk-entry prefix (redundant per wave; per-lane n) ---
  const float aL = powA[(CL - 1) * SD + n];
  float p = state0[(b * NG + g) * SD + n];
  {
    int cc = 0;
    while (cc + 8 <= c) {
      float ca[8];
      #pragma unroll
      for (int e = 0; e < 8; ++e)
        ca[e] = carry[((b * NC + cc + e) * NG + g) * SD + n];
      #pragma unroll
      for (int e = 0; e < 8; ++e) p = fmaf(p, aL, ca[e]);
      cc += 8;
    }
    for (; cc < c; ++cc)
      p = fmaf(p, aL, carry[((b * NC + cc) * NG + g) * SD + n]);
  }
  __shared__ float sPref[SD];
  if (tid < SD) sPref[tid] = p;
  if (c == NC - 1 && tid < SD)
    sfin[(b * NG + g) * SD + tid] = fmaf(p, aL, carry[((b * NC + (NC - 1)) * NG + g) * SD + tid]);
  __syncthreads();

  // --- corrected state fragments (B operand: col=t, k=n) ---
  short8 sf[4];
  {
    float pr[8];
    #pragma unroll
    for (int e = 0; e < 8; ++e) pr[e] = sPref[lh * 8 + e];
    #pragma unroll
    for (int tt = 0; tt < 4; ++tt) {
      int t = tt * 16 + lr;
      short8 sl = *(const short8*)(stg + t * SD + lh * 8);
      const float* pw = powA + t * SD + lh * 8;
      float4 pw0 = *(const float4*)pw;
      float4 pw1 = *(const float4*)(pw + 4);
      short8 hh;
      hh[0] = (short)f2bf(bf2f((unsigned short)sl[0]) + pw0.x * pr[0]);
      hh[1] = (short)f2bf(bf2f((unsigned short)sl[1]) + pw0.y * pr[1]);
      hh[2] = (short)f2bf(bf2f((unsigned short)sl[2]) + pw0.z * pr[2]);
      hh[3] = (short)f2bf(bf2f((unsigned short)sl[3]) + pw0.w * pr[3]);
      hh[4] = (short)f2bf(bf2f((unsigned short)sl[4]) + pw1.x * pr[4]);
      hh[5] = (short)f2bf(bf2f((unsigned short)sl[5]) + pw1.y * pr[5]);
      hh[6] = (short)f2bf(bf2f((unsigned short)sl[6]) + pw1.z * pr[6]);
      hh[7] = (short)f2bf(bf2f((unsigned short)sl[7]) + pw1.w * pr[7]);
      sf[tt] = hh;
    }
  }

  // --- GEMM (swapped): D[d][t] = sum_n C[d][n]*s[t][n]; this wave: d-tiles w, w+4 ---
  const float* cp = C + (size_t)g * GD * SD;
  const size_t rowbase = ((size_t)b * TT + (size_t)c * CL) * DM + g * GD;

  #pragma unroll
  for (int hh = 0; hh < 2; ++hh) {
    const int ht = w + hh * 4;               // d-tile 0..7
    const int d = ht * 16 + lr;
    const float* pp = cp + (size_t)d * SD + lh * 8;
    float4 v0 = *(const float4*)pp;
    float4 v1 = *(const float4*)(pp + 4);
    short8 cf = pack8(v0, v1);

    f32x4 acc[4];
    #pragma unroll
    for (int tt = 0; tt < 4; ++tt) {
      f32x4 z;
      #pragma unroll
      for (int j = 0; j < 4; ++j) z[j] = 0.f;
      acc[tt] = __builtin_amdgcn_mfma_f32_16x16x32_bf16(cf, sf[tt], z, 0, 0, 0);
    }

    // epilogue: y = Cs + Dp*u (float4); lane's 4 acc are consecutive d
    const int d0 = ht * 16 + lh * 4;
    float4 dp4 = *(const float4*)(Dp + g * GD + d0);
    #pragma unroll
    for (int tt = 0; tt < 4; ++tt) {
      int t = tt * 16 + lr;
      size_t off = rowbase + (size_t)t * DM + d0;
      float4 u4 = *(const float4*)(u + off);
      float4 r;
      r.x = acc[tt][0] + dp4.x * u4.x;
      r.y = acc[tt][1] + dp4.y * u4.y;
      r.z = acc[tt][2] + dp4.z * u4.z;
      r.w = acc[tt][3] + dp4.w * u4.w;
      *(float4*)(y + off) = r;
    }
  }
}

extern "C" void kernel_launch(void* const* d_in, const int* in_sizes, int n_in,
                              void* d_out, int out_size, void* d_ws, size_t ws_size,
                              hipStream_t stream) {
  const float* u       = (const float*)d_in[0];
  const float* state0  = (const float*)d_in[1];
  const float* A_log   = (const float*)d_in[2];
  const float* B_param = (const float*)d_in[3];
  const float* C       = (const float*)d_in[4];
  const float* Dp      = (const float*)d_in[5];
  const float* dtl     = (const float*)d_in[6];
  float* y = (float*)d_out;
  unsigned char* ws = (unsigned char*)d_ws;
  float* sfin = y + (size_t)BS * TT * DM;

  ka_bu_scan<<<dim3(BS * NG * NC), dim3(256), 0, stream>>>(u, A_log, B_param, dtl, ws);
  kb_y<<<dim3(BS * NG * NC), dim3(256), 0, stream>>>(u, state0, C, Dp, ws, y, sfin);
}

// Round 4
// 55.437 us; speedup vs baseline: 1.1822x; 1.1822x over previous
//
#include <hip/hip_runtime.h>
#include <hip/hip_bf16.h>

#define DM 1024
#define SD 32
#define NG 8
#define GD 128
#define BS 4
#define TT 4096
#define CL 64        // chunk length
#define NC (TT/CL)   // 64 chunks

typedef __attribute__((ext_vector_type(8))) short short8;
typedef __attribute__((ext_vector_type(4))) float f32x4;

// workspace layout (bytes), 16B aligned
#define WS_POWA  0                         // f32[8][64][32]  = 64KB  (powA[g][t][n] = Abar^(t+1))
#define WS_STL   65536                     // bf16[4][64][8][64][32] = 8MB (local-scan states)
#define WS_CARRY (WS_STL + 8388608)        // f32[4][64][8][32] = 256KB
#define WS_PAL   (WS_CARRY + 262144)       // f32[8][64][32] = 64KB (powAL[g][j][n] = (a^64)^j)

__device__ __forceinline__ unsigned short f2bf(float f) {
  unsigned u = __float_as_uint(f);
  unsigned r = (u + 0x7FFFu + ((u >> 16) & 1u)) >> 16;   // RNE
  return (unsigned short)r;
}
__device__ __forceinline__ float bf2f(unsigned short h) {
  return __uint_as_float(((unsigned)h) << 16);
}
__device__ __forceinline__ float softplus_f(float x) {
  return (x > 20.f) ? x : log1pf(expf(x));
}
__device__ __forceinline__ short8 pack8(float4 a, float4 b) {
  short8 h;
  h[0]=(short)f2bf(a.x); h[1]=(short)f2bf(a.y); h[2]=(short)f2bf(a.z); h[3]=(short)f2bf(a.w);
  h[4]=(short)f2bf(b.x); h[5]=(short)f2bf(b.y); h[6]=(short)f2bf(b.z); h[7]=(short)f2bf(b.w);
  return h;
}

// ---------------- KA: Bu GEMM (reg-direct) + local scan (+powA/powAL for 8 blocks) ----------------
__global__ __launch_bounds__(64) void ka_bu_scan(const float* __restrict__ u,
                                                 const float* __restrict__ A_log,
                                                 const float* __restrict__ B_param,
                                                 const float* __restrict__ dt_logit,
                                                 unsigned char* __restrict__ ws) {
  const int bx = blockIdx.x;
  const int c = bx & (NC - 1);
  const int g = (bx >> 6) & (NG - 1);
  const int b = bx >> 9;
  const int l = threadIdx.x;
  const int lr = l & 15, lh = l >> 4;

  const float dtg = 0.001f + 0.099f * (1.f / (1.f + expf(-dt_logit[g])));

  // frac for the two B-operand n's this lane touches (n = nt*16 + lr)
  float fracv[2];
  #pragma unroll
  for (int nt = 0; nt < 2; ++nt) {
    int n = nt * 16 + lr;
    float A = -softplus_f(A_log[g * SD + n]);
    float a = expf(A * dtg);
    fracv[nt] = (fabsf(A) > 1e-6f) ? (a - 1.f) / A : dtg;
  }
  // scan decay for n = l&31
  float a_scan;
  {
    float A = -softplus_f(A_log[g * SD + (l & 31)]);
    a_scan = expf(A * dtg);
  }

  // B fragments: Bbar[n][i] = frac_n * B_param[g][n][i], n = nt*16+lr, i = kt*32 + lh*8 ..+7
  const float* bp = B_param + (size_t)g * SD * GD;
  short8 bfr[4][2];
  #pragma unroll
  for (int kt = 0; kt < 4; ++kt)
    #pragma unroll
    for (int nt = 0; nt < 2; ++nt) {
      const float* p = bp + (size_t)(nt * 16 + lr) * GD + kt * 32 + lh * 8;
      float4 v0 = *(const float4*)p;
      float4 v1 = *(const float4*)(p + 4);
      float s = fracv[nt];
      v0.x*=s; v0.y*=s; v0.z*=s; v0.w*=s;
      v1.x*=s; v1.y*=s; v1.z*=s; v1.w*=s;
      bfr[kt][nt] = pack8(v0, v1);
    }

  // A fragments streamed from global: u[t][i], t = m*16+lr, i = kt*32+lh*8
  const float* up = u + ((size_t)b * TT + (size_t)c * CL) * DM + g * GD;
  f32x4 acc[4][2];
  #pragma unroll
  for (int m = 0; m < 4; ++m)
    #pragma unroll
    for (int nt = 0; nt < 2; ++nt)
      #pragma unroll
      for (int j = 0; j < 4; ++j) acc[m][nt][j] = 0.f;

  #pragma unroll
  for (int kt = 0; kt < 4; ++kt) {
    short8 af[4];
    #pragma unroll
    for (int m = 0; m < 4; ++m) {
      const float* p = up + (size_t)(m * 16 + lr) * DM + kt * 32 + lh * 8;
      float4 v0 = *(const float4*)p;
      float4 v1 = *(const float4*)(p + 4);
      af[m] = pack8(v0, v1);
    }
    #pragma unroll
    for (int m = 0; m < 4; ++m)
      #pragma unroll
      for (int nt = 0; nt < 2; ++nt)
        acc[m][nt] = __builtin_amdgcn_mfma_f32_16x16x32_bf16(af[m], bfr[kt][nt], acc[m][nt], 0, 0, 0);
  }

  // hand Bu to the scan via LDS
  __shared__ __align__(16) float sBu[CL * 33];            // 8448B
  __shared__ __align__(16) unsigned short sSt[CL * SD];   // 4096B
  #pragma unroll
  for (int m = 0; m < 4; ++m)
    #pragma unroll
    for (int nt = 0; nt < 2; ++nt)
      #pragma unroll
      for (int j = 0; j < 4; ++j) {
        int t = m * 16 + lh * 4 + j;   // C/D: row = (lane>>4)*4 + j
        int n = nt * 16 + lr;          //      col = lane&15
        sBu[t * 33 + n] = acc[m][nt][j];
      }
  __syncthreads();

  float* carry = (float*)(ws + WS_CARRY);
  if (l < SD) {
    float s = 0.f;
    #pragma unroll
    for (int t = 0; t < CL; ++t) {
      s = fmaf(s, a_scan, sBu[t * 33 + l]);
      sSt[t * SD + l] = f2bf(s);
    }
    carry[((b * NC + c) * NG + g) * SD + l] = s;
  }
  __syncthreads();

  // states -> global (bf16), coalesced
  unsigned short* stg = (unsigned short*)(ws + WS_STL) + ((size_t)((b * NC + c) * NG + g)) * CL * SD;
  #pragma unroll
  for (int p = 0; p < 4; ++p) {
    int off = (p * 64 + l) * 8;        // 2048 ushorts
    *(short8*)(stg + off) = *(short8*)(sSt + off);
  }

  // 8 special blocks (b==0,c==0) emit powA and powAL tables for KB
  if (b == 0 && c == 0 && l < SD) {
    float* powA = (float*)(ws + WS_POWA);
    float* powAL = (float*)(ws + WS_PAL);
    float p = 1.f;
    #pragma unroll
    for (int t = 0; t < CL; ++t) {
      p *= a_scan;
      powA[(g * CL + t) * SD + l] = p;
    }
    float aL = p;                       // a^64
    float q = 1.f;
    #pragma unroll
    for (int j = 0; j < CL; ++j) {
      powAL[(g * CL + j) * SD + l] = q; // aL^j, j=0 -> 1
      q *= aL;
    }
  }
}

// ---------------- KB: parallel prefix (weighted sum) + correction + C GEMM + Dp*u + y ----------------
__global__ __launch_bounds__(64) void kb_y(const float* __restrict__ u,
                                           const float* __restrict__ state0,
                                           const float* __restrict__ C,
                                           const float* __restrict__ Dp,
                                           unsigned char* __restrict__ ws,
                                           float* __restrict__ y,
                                           float* __restrict__ sfin) {
  const int bx = blockIdx.x;
  const int c = bx & (NC - 1);
  const int g = (bx >> 6) & (NG - 1);
  const int b = bx >> 9;
  const int l = threadIdx.x;
  const int lr = l & 15, lh = l >> 4;
  const int n = l & 31;

  const float* powA = (const float*)(ws + WS_POWA) + g * CL * SD;
  const float* powAL = (const float*)(ws + WS_PAL) + g * CL * SD;
  const float* carry = (const float*)(ws + WS_CARRY);
  const unsigned short* stg = (const unsigned short*)(ws + WS_STL) + ((size_t)((b * NC + c) * NG + g)) * CL * SD;

  // --- chunk-entry prefix: p = state0*aL^c + sum_{cc<c} aL^(c-1-cc)*carry_cc ---
  // fully parallel: independent loads, 4 accumulators, no serial chain
  float p;
  {
    float a0 = 0.f, a1 = 0.f, a2 = 0.f, a3 = 0.f;
    int cc = 0;
    while (cc + 8 <= c) {
      float ca[8], w[8];
      #pragma unroll
      for (int e = 0; e < 8; ++e) {
        ca[e] = carry[((b * NC + cc + e) * NG + g) * SD + n];
        w[e]  = powAL[(c - 1 - cc - e) * SD + n];
      }
      a0 = fmaf(w[0], ca[0], a0); a1 = fmaf(w[1], ca[1], a1);
      a2 = fmaf(w[2], ca[2], a2); a3 = fmaf(w[3], ca[3], a3);
      a0 = fmaf(w[4], ca[4], a0); a1 = fmaf(w[5], ca[5], a1);
      a2 = fmaf(w[6], ca[6], a2); a3 = fmaf(w[7], ca[7], a3);
      cc += 8;
    }
    for (; cc < c; ++cc)
      a0 = fmaf(powAL[(c - 1 - cc) * SD + n], carry[((b * NC + cc) * NG + g) * SD + n], a0);
    p = fmaf(state0[(b * NG + g) * SD + n], powAL[c * SD + n], (a0 + a1) + (a2 + a3));
  }
  __shared__ float sPref[SD];
  if (l < SD) sPref[l] = p;
  if (c == NC - 1 && l < SD) {
    const float aL = powA[(CL - 1) * SD + l];
    sfin[(b * NG + g) * SD + l] = fmaf(p, aL, carry[((b * NC + (NC - 1)) * NG + g) * SD + l]);
  }
  __syncthreads();

  // --- corrected state fragments (B operand, col = t, k = n) ---
  // s_true[t][n] = s_loc + a^(t+1) * pref[n];  lane: t = tt*16+lr, n = lh*8 ..+7
  short8 sf[4];
  {
    float pr[8];
    #pragma unroll
    for (int e = 0; e < 8; ++e) pr[e] = sPref[lh * 8 + e];
    #pragma unroll
    for (int tt = 0; tt < 4; ++tt) {
      int t = tt * 16 + lr;
      short8 sl = *(const short8*)(stg + t * SD + lh * 8);
      const float* pw = powA + t * SD + lh * 8;
      float4 pw0 = *(const float4*)pw;
      float4 pw1 = *(const float4*)(pw + 4);
      short8 hh;
      hh[0] = (short)f2bf(bf2f((unsigned short)sl[0]) + pw0.x * pr[0]);
      hh[1] = (short)f2bf(bf2f((unsigned short)sl[1]) + pw0.y * pr[1]);
      hh[2] = (short)f2bf(bf2f((unsigned short)sl[2]) + pw0.z * pr[2]);
      hh[3] = (short)f2bf(bf2f((unsigned short)sl[3]) + pw0.w * pr[3]);
      hh[4] = (short)f2bf(bf2f((unsigned short)sl[4]) + pw1.x * pr[4]);
      hh[5] = (short)f2bf(bf2f((unsigned short)sl[5]) + pw1.y * pr[5]);
      hh[6] = (short)f2bf(bf2f((unsigned short)sl[6]) + pw1.z * pr[6]);
      hh[7] = (short)f2bf(bf2f((unsigned short)sl[7]) + pw1.w * pr[7]);
      sf[tt] = hh;
    }
  }

  // --- GEMM with swapped operands: D[d][t] = sum_n C[d][n] * s[t][n] ---
  const float* cp = C + (size_t)g * GD * SD;
  const size_t rowbase = ((size_t)b * TT + (size_t)c * CL) * DM + g * GD;

  #pragma unroll
  for (int h = 0; h < 2; ++h) {
    short8 cf[4];
    #pragma unroll
    for (int dd = 0; dd < 4; ++dd) {
      int d = (h * 4 + dd) * 16 + lr;
      const float* pp = cp + (size_t)d * SD + lh * 8;
      float4 v0 = *(const float4*)pp;
      float4 v1 = *(const float4*)(pp + 4);
      cf[dd] = pack8(v0, v1);
    }
    f32x4 acc[4][4];
    #pragma unroll
    for (int dd = 0; dd < 4; ++dd)
      #pragma unroll
      for (int tt = 0; tt < 4; ++tt) {
        #pragma unroll
        for (int j = 0; j < 4; ++j) acc[dd][tt][j] = 0.f;
        acc[dd][tt] = __builtin_amdgcn_mfma_f32_16x16x32_bf16(cf[dd], sf[tt], acc[dd][tt], 0, 0, 0);
      }
    // epilogue: y = Cs + Dp*u, vectorized float4
    #pragma unroll
    for (int dd = 0; dd < 4; ++dd) {
      int d0 = (h * 4 + dd) * 16 + lh * 4;
      float4 dp4 = *(const float4*)(Dp + g * GD + d0);
      #pragma unroll
      for (int tt = 0; tt < 4; ++tt) {
        int t = tt * 16 + lr;
        size_t off = rowbase + (size_t)t * DM + d0;
        float4 u4 = *(const float4*)(u + off);
        float4 r;
        r.x = acc[dd][tt][0] + dp4.x * u4.x;
        r.y = acc[dd][tt][1] + dp4.y * u4.y;
        r.z = acc[dd][tt][2] + dp4.z * u4.z;
        r.w = acc[dd][tt][3] + dp4.w * u4.w;
        *(float4*)(y + off) = r;
      }
    }
  }
}

extern "C" void kernel_launch(void* const* d_in, const int* in_sizes, int n_in,
                              void* d_out, int out_size, void* d_ws, size_t ws_size,
                              hipStream_t stream) {
  const float* u       = (const float*)d_in[0];
  const float* state0  = (const float*)d_in[1];
  const float* A_log   = (const float*)d_in[2];
  const float* B_param = (const float*)d_in[3];
  const float* C       = (const float*)d_in[4];
  const float* Dp      = (const float*)d_in[5];
  const float* dtl     = (const float*)d_in[6];
  float* y = (float*)d_out;
  unsigned char* ws = (unsigned char*)d_ws;
  float* sfin = y + (size_t)BS * TT * DM;

  ka_bu_scan<<<dim3(BS * NG * NC), dim3(64), 0, stream>>>(u, A_log, B_param, dtl, ws);
  kb_y<<<dim3(BS * NG * NC), dim3(64), 0, stream>>>(u, state0, C, Dp, ws, y, sfin);
}